// Round 1
// baseline (969.427 us; speedup 1.0000x reference)
//
#include <hip/hip_runtime.h>

#define T_ 6
#define B_ 8
#define C_ 192
#define H_ 112
#define W_ 112
#define K_ 3
#define H0_ 56
#define W0_ 56
#define N_ (T_ * K_)      // 18
#define HW_ (H_ * W_)     // 12544
#define HW0_ (H0_ * W0_)  // 3136

// ---------------------------------------------------------------------------
// Kernel A: pack 3 binary masks into a 3-bit code per (b,t,h0,w0).
// gcn_masks: [B,T,K,H0,W0] int32
// ---------------------------------------------------------------------------
__global__ __launch_bounds__(256) void build_code_kernel(
    const int* __restrict__ masks, unsigned char* __restrict__ code) {
  int idx = blockIdx.x * 256 + threadIdx.x;  // over B*T*H0*W0 = 150528
  if (idx >= B_ * T_ * HW0_) return;
  int p = idx % HW0_;
  int bt = idx / HW0_;  // b*T + t
  const int base = bt * K_ * HW0_;
  int c0 = masks[base + 0 * HW0_ + p];
  int c1 = masks[base + 1 * HW0_ + p];
  int c2 = masks[base + 2 * HW0_ + p];
  code[idx] = (unsigned char)((c0 & 1) | ((c1 & 1) << 1) | ((c2 & 1) << 2));
}

// ---------------------------------------------------------------------------
// Kernel B: masked pooling. One block per (t,b,c) plane (x layout order).
// feat[b][t][k][c] = sum_{h,w} x[t,b,c,h,w] * m[b,t,k,h,w]   (NOT yet / HW)
// ---------------------------------------------------------------------------
__global__ __launch_bounds__(256) void pool_kernel(
    const float* __restrict__ x, const unsigned char* __restrict__ code,
    float* __restrict__ feat) {
  int blk = blockIdx.x;  // (t*B + b)*C + c
  int c = blk % C_;
  int tb = blk / C_;  // t*B + b
  int b = tb % B_;
  int t = tb / B_;

  const float4* xp = (const float4*)(x + (size_t)blk * HW_);
  const unsigned char* cp = code + (b * T_ + t) * HW0_;

  float s0 = 0.f, s1 = 0.f, s2 = 0.f;
  // W_=112 divisible by 4 -> each float4 stays within one row.
  for (int i = threadIdx.x; i < HW_ / 4; i += 256) {
    float4 v = xp[i];
    int p = i * 4;
    int h = p / W_;
    int w = p - h * W_;
    const unsigned char* crow = cp + (h >> 1) * W0_ + (w >> 1);
    int ca = crow[0];  // covers pixels w, w+1
    int cb = crow[1];  // covers pixels w+2, w+3
    float pa = v.x + v.y;
    float pb = v.z + v.w;
    s0 += (ca & 1 ? pa : 0.f) + (cb & 1 ? pb : 0.f);
    s1 += (ca & 2 ? pa : 0.f) + (cb & 2 ? pb : 0.f);
    s2 += (ca & 4 ? pa : 0.f) + (cb & 4 ? pb : 0.f);
  }

  // wave (64-lane) reduce, then LDS across the 4 waves
  for (int off = 32; off > 0; off >>= 1) {
    s0 += __shfl_down(s0, off);
    s1 += __shfl_down(s1, off);
    s2 += __shfl_down(s2, off);
  }
  __shared__ float red[4][3];
  int lane = threadIdx.x & 63;
  int wid = threadIdx.x >> 6;
  if (lane == 0) {
    red[wid][0] = s0;
    red[wid][1] = s1;
    red[wid][2] = s2;
  }
  __syncthreads();
  if (threadIdx.x == 0) {
    float f0 = red[0][0] + red[1][0] + red[2][0] + red[3][0];
    float f1 = red[0][1] + red[1][1] + red[2][1] + red[3][1];
    float f2 = red[0][2] + red[1][2] + red[2][2] + red[3][2];
    float* fb = feat + ((b * T_ + t) * K_) * C_ + c;
    fb[0 * C_] = f0;
    fb[1 * C_] = f1;
    fb[2 * C_] = f2;
  }
}

// ---------------------------------------------------------------------------
// Kernel C: per-batch GCN. One block per b (grid = 8), 256 threads.
// node = feat/(H*W); adj = softmax(node node^T); aaa = node W_emb^T;
// support = aaa W_gcn; outk = adj support + b_gcn
// ---------------------------------------------------------------------------
__global__ __launch_bounds__(256) void gcn_kernel(
    const float* __restrict__ feat, const float* __restrict__ W_emb,
    const float* __restrict__ W_gcn, const float* __restrict__ b_gcn,
    float* __restrict__ outk) {
  int b = blockIdx.x;
  int tid = threadIdx.x;
  __shared__ float node[N_][C_];
  __shared__ float aaa[N_][C_];
  __shared__ float sup[N_][C_];
  __shared__ float adj[N_][N_];

  const float inv_hw = 1.0f / (float)HW_;
  for (int i = tid; i < N_ * C_; i += 256)
    node[i / C_][i % C_] = feat[b * N_ * C_ + i] * inv_hw;
  __syncthreads();

  // gram
  for (int i = tid; i < N_ * N_; i += 256) {
    int n = i / N_, m = i % N_;
    float s = 0.f;
    for (int c = 0; c < C_; ++c) s += node[n][c] * node[m][c];
    adj[n][m] = s;
  }
  __syncthreads();

  // softmax rows (18 rows, one thread each)
  if (tid < N_) {
    float mx = -1e30f;
    for (int m = 0; m < N_; ++m) mx = fmaxf(mx, adj[tid][m]);
    float tmp[N_];
    float sum = 0.f;
    for (int m = 0; m < N_; ++m) {
      tmp[m] = __expf(adj[tid][m] - mx);
      sum += tmp[m];
    }
    float inv = 1.0f / sum;
    for (int m = 0; m < N_; ++m) adj[tid][m] = tmp[m] * inv;
  }
  __syncthreads();

  // aaa[n][d] = sum_c node[n][c] * W_emb[d][c]
  for (int i = tid; i < N_ * C_; i += 256) {
    int n = i / C_, d = i % C_;
    const float* we = W_emb + d * C_;
    float s = 0.f;
    for (int c = 0; c < C_; ++c) s += node[n][c] * we[c];
    aaa[n][d] = s;
  }
  __syncthreads();

  // support[n][e] = sum_d aaa[n][d] * W_gcn[d][e]
  for (int i = tid; i < N_ * C_; i += 256) {
    int n = i / C_, e = i % C_;
    float s = 0.f;
    for (int d = 0; d < C_; ++d) s += aaa[n][d] * W_gcn[d * C_ + e];
    sup[n][e] = s;
  }
  __syncthreads();

  // outk[n][e] = sum_m adj[n][m] * support[m][e] + b_gcn[e]
  for (int i = tid; i < N_ * C_; i += 256) {
    int n = i / C_, e = i % C_;
    float s = b_gcn[e];
    for (int m = 0; m < N_; ++m) s += adj[n][m] * sup[m][e];
    outk[b * N_ * C_ + i] = s;
  }
}

// ---------------------------------------------------------------------------
// Kernel D: out = x + sum_k outk[b,t,k,c] * m[b,t,k,h,w]. One block per (t,b,c).
// ---------------------------------------------------------------------------
__global__ __launch_bounds__(256) void out_kernel(
    const float* __restrict__ x, const unsigned char* __restrict__ code,
    const float* __restrict__ outk, float* __restrict__ out) {
  int blk = blockIdx.x;  // (t*B + b)*C + c
  int c = blk % C_;
  int tb = blk / C_;
  int b = tb % B_;
  int t = tb / B_;

  const float* ob = outk + ((b * T_ + t) * K_) * C_ + c;
  float o0 = ob[0 * C_], o1 = ob[1 * C_], o2 = ob[2 * C_];

  const float4* xp = (const float4*)(x + (size_t)blk * HW_);
  float4* op = (float4*)(out + (size_t)blk * HW_);
  const unsigned char* cp = code + (b * T_ + t) * HW0_;

  for (int i = threadIdx.x; i < HW_ / 4; i += 256) {
    float4 v = xp[i];
    int p = i * 4;
    int h = p / W_;
    int w = p - h * W_;
    const unsigned char* crow = cp + (h >> 1) * W0_ + (w >> 1);
    int ca = crow[0];
    int cb = crow[1];
    float addA = (ca & 1 ? o0 : 0.f) + (ca & 2 ? o1 : 0.f) + (ca & 4 ? o2 : 0.f);
    float addB = (cb & 1 ? o0 : 0.f) + (cb & 2 ? o1 : 0.f) + (cb & 4 ? o2 : 0.f);
    v.x += addA;
    v.y += addA;
    v.z += addB;
    v.w += addB;
    op[i] = v;
  }
}

extern "C" void kernel_launch(void* const* d_in, const int* in_sizes, int n_in,
                              void* d_out, int out_size, void* d_ws,
                              size_t ws_size, hipStream_t stream) {
  const float* x = (const float*)d_in[0];
  const int* masks = (const int*)d_in[1];
  const float* W_emb = (const float*)d_in[2];
  const float* W_gcn = (const float*)d_in[3];
  const float* b_gcn = (const float*)d_in[4];
  float* out = (float*)d_out;

  // workspace layout (all 256-aligned):
  //   code: B*T*H0*W0 bytes = 150528
  //   feat: B*T*K*C floats  = 110592 bytes
  //   outk: B*T*K*C floats  = 110592 bytes
  unsigned char* code = (unsigned char*)d_ws;
  float* feat = (float*)((char*)d_ws + 150528);
  float* outk = (float*)((char*)d_ws + 150528 + 110592);

  {
    int n = B_ * T_ * HW0_;
    build_code_kernel<<<(n + 255) / 256, 256, 0, stream>>>(masks, code);
  }
  pool_kernel<<<T_ * B_ * C_, 256, 0, stream>>>(x, code, feat);
  gcn_kernel<<<B_, 256, 0, stream>>>(feat, W_emb, W_gcn, b_gcn, outk);
  out_kernel<<<T_ * B_ * C_, 256, 0, stream>>>(x, code, outk, out);
}